// Round 1
// baseline (212.699 us; speedup 1.0000x reference)
//
#include <hip/hip_runtime.h>

typedef unsigned short u16;
typedef __attribute__((ext_vector_type(8))) unsigned short u16x8;
typedef __attribute__((ext_vector_type(8))) __bf16 bf16x8;
typedef __attribute__((ext_vector_type(4))) float f32x4;

#define SEQ 2048
#define DMODEL 1024
#define LDP 3072

__device__ __forceinline__ u16 f2bf(float f) {
  unsigned u = __builtin_bit_cast(unsigned, f);
  u = (u + 0x7fffu + ((u >> 16) & 1u)) >> 16;
  return (u16)u;
}

__device__ __forceinline__ bf16x8 ldbf8(const u16* p) {
  return __builtin_bit_cast(bf16x8, *(const u16x8*)p);
}

__device__ __forceinline__ f32x4 mfma16(bf16x8 a, bf16x8 b, f32x4 c) {
  return __builtin_amdgcn_mfma_f32_16x16x32_bf16(a, b, c, 0, 0, 0);
}

// ----------------- fp32 -> bf16 casts -----------------
__device__ __forceinline__ void cast8(const float* __restrict__ s, u16* __restrict__ d) {
  const size_t i = ((size_t)blockIdx.x * blockDim.x + threadIdx.x) * 8;
  const float4 a = *(const float4*)(s + i);
  const float4 b = *(const float4*)(s + i + 4);
  u16x8 o;
  o[0] = f2bf(a.x); o[1] = f2bf(a.y); o[2] = f2bf(a.z); o[3] = f2bf(a.w);
  o[4] = f2bf(b.x); o[5] = f2bf(b.y); o[6] = f2bf(b.z); o[7] = f2bf(b.w);
  *(u16x8*)(d + i) = o;
}

__global__ void cast_qkv_k(const float* __restrict__ q, const float* __restrict__ k,
                           const float* __restrict__ v, u16* __restrict__ dq,
                           u16* __restrict__ dk, u16* __restrict__ dv) {
  const int z = blockIdx.y;
  cast8(z == 0 ? q : z == 1 ? k : v, z == 0 ? dq : z == 1 ? dk : dv);
}

__global__ void cast_w_k(const float* __restrict__ wq, const float* __restrict__ wk,
                         const float* __restrict__ wv, const float* __restrict__ wo,
                         u16* __restrict__ wqkv, u16* __restrict__ wob) {
  const int z = blockIdx.y;
  const float* s = z == 0 ? wq : z == 1 ? wk : z == 2 ? wv : wo;
  u16* d = z < 3 ? wqkv + (size_t)z * (DMODEL * DMODEL) : wob;
  cast8(s, d);
}

// ----------------- GEMM: C = A @ B^T + bias -----------------
// A:[M,K] bf16 row-major; B:[N,K] bf16 row-major (torch Linear weight layout).
// OMODE 0: fp32 out row-major (ldc). 1: bf16 out row-major (ldc, +ncol0).
// OMODE 2: bf16 out scattered as vT[b,h,d,s] (V projection, pre-transposed).
template <int OMODE>
__device__ __forceinline__ void gemm_bt_body(const u16* __restrict__ A,
                                             const u16* __restrict__ Bw,
                                             const float* __restrict__ bias,
                                             void* __restrict__ Cv, const int K,
                                             const int ldc, const int ncol0) {
  __shared__ u16 As[128 * 56];  // pad 32->56: 112B rows, 16B aligned, ~2-way banks
  __shared__ u16 Bs[128 * 56];
  const int tid = threadIdx.x;
  const int lane = tid & 63;
  const int w = tid >> 6;
  const int m0 = blockIdx.y * 128;
  const int n0 = blockIdx.x * 128;
  const int l15 = lane & 15;
  const int lg = lane >> 4;

  f32x4 acc[4][4] = {};

  const int arow = (w >> 1) * 64 + l15;
  const int brow = (w & 1) * 64 + l15;
  const int kf = lg * 8;

  const int sr = tid >> 2;        // 0..63 staging row
  const int sc = (tid & 3) * 8;   // staging col (elements)
  const u16* Ag = A + (size_t)(m0 + sr) * K + sc;
  const u16* Bg = Bw + (size_t)(n0 + sr) * K + sc;

  for (int k0 = 0; k0 < K; k0 += 32) {
    const u16x8 a0 = *(const u16x8*)(Ag + k0);
    const u16x8 a1 = *(const u16x8*)(Ag + k0 + (size_t)64 * K);
    const u16x8 b0 = *(const u16x8*)(Bg + k0);
    const u16x8 b1 = *(const u16x8*)(Bg + k0 + (size_t)64 * K);
    __syncthreads();  // prior iter's LDS reads done
    *(u16x8*)&As[sr * 56 + sc] = a0;
    *(u16x8*)&As[(sr + 64) * 56 + sc] = a1;
    *(u16x8*)&Bs[sr * 56 + sc] = b0;
    *(u16x8*)&Bs[(sr + 64) * 56 + sc] = b1;
    __syncthreads();
    bf16x8 af[4], bfv[4];
#pragma unroll
    for (int t = 0; t < 4; ++t) {
      af[t] = ldbf8(&As[(arow + t * 16) * 56 + kf]);
      bfv[t] = ldbf8(&Bs[(brow + t * 16) * 56 + kf]);
    }
#pragma unroll
    for (int i = 0; i < 4; ++i)
#pragma unroll
      for (int j = 0; j < 4; ++j) acc[i][j] = mfma16(af[i], bfv[j], acc[i][j]);
  }

  const int mrow = (w >> 1) * 64 + lg * 4;
  const int ncol = (w & 1) * 64 + l15;
#pragma unroll
  for (int j = 0; j < 4; ++j) {
    const int gn = n0 + ncol + j * 16;
    const float bia = bias[gn];
#pragma unroll
    for (int i = 0; i < 4; ++i) {
      const int gmb = m0 + mrow + i * 16;
#pragma unroll
      for (int r = 0; r < 4; ++r) {
        const float val = acc[i][j][r] + bia;
        const int gm = gmb + r;
        if (OMODE == 0) {
          ((float*)Cv)[(size_t)gm * ldc + gn] = val;
        } else if (OMODE == 1) {
          ((u16*)Cv)[(size_t)gm * ldc + ncol0 + gn] = f2bf(val);
        } else {
          const int bb = gm >> 11, ss = gm & 2047;
          const int hh = gn >> 6, dd = gn & 63;
          ((u16*)Cv)[(((size_t)(bb * 16 + hh) * 64 + dd) << 11) + ss] = f2bf(val);
        }
      }
    }
  }
}

__global__ __launch_bounds__(256, 2) void gemm_qk_k(
    const u16* __restrict__ qb, const u16* __restrict__ kb,
    const u16* __restrict__ wqkv, const float* __restrict__ bq,
    const float* __restrict__ bk, u16* __restrict__ proj) {
  const int z = blockIdx.z;
  gemm_bt_body<1>(z == 0 ? qb : kb, wqkv + (size_t)z * (DMODEL * DMODEL),
                  z == 0 ? bq : bk, proj, DMODEL, LDP, z * DMODEL);
}

__global__ __launch_bounds__(256, 2) void gemm_v_k(const u16* __restrict__ vb,
                                                   const u16* __restrict__ wv,
                                                   const float* __restrict__ bv,
                                                   u16* __restrict__ vtb) {
  gemm_bt_body<2>(vb, wv, bv, vtb, DMODEL, 0, 0);
}

__global__ __launch_bounds__(256, 2) void gemm_o_k(const u16* __restrict__ attnb,
                                                   const u16* __restrict__ wob,
                                                   const float* __restrict__ bo,
                                                   float* __restrict__ out) {
  gemm_bt_body<0>(attnb, wob, bo, out, DMODEL, DMODEL, 0);
}

// ----------------- flash attention -----------------
// grid (SEQ/64, B*H); 4 waves; wave w owns Q rows qB+w*16..+15.
__global__ __launch_bounds__(256, 2) void attn_k(const u16* __restrict__ proj,
                                                 const u16* __restrict__ vtb,
                                                 u16* __restrict__ outa) {
  __shared__ u16 ks[64 * 72];     // K tile [kv][d], pad 72
  __shared__ u16 vt[64 * 72];     // V^T tile [d][kv], pad 72
  __shared__ u16 ps[4][16 * 72];  // per-wave P [16 q][64 kv], pad 72
  const int tid = threadIdx.x;
  const int lane = tid & 63;
  const int w = tid >> 6;
  const int qB = blockIdx.x * 64;
  const int bh = blockIdx.y;
  const size_t rb = (size_t)(bh >> 4) * SEQ;
  const int h = bh & 15;
  const int l15 = lane & 15;
  const int lg = lane >> 4;
  const int dfr = lg * 8;

  const u16* qp = proj + (rb + qB + w * 16 + l15) * LDP + h * 64 + dfr;
  const bf16x8 qf0 = ldbf8(qp);
  const bf16x8 qf1 = ldbf8(qp + 32);

  f32x4 oacc[4] = {};
  float mrun[4], lrun[4];
#pragma unroll
  for (int r = 0; r < 4; ++r) { mrun[r] = -3.0e38f; lrun[r] = 0.f; }

  const int sr = tid >> 3;         // 0..31
  const int scc = (tid & 7) * 8;
  const u16* kgb = proj + rb * LDP + DMODEL + h * 64;  // K section
  const u16* vgb = vtb + (size_t)bh * 64 * SEQ;        // [d][s]

  for (int kv0 = 0; kv0 < SEQ; kv0 += 64) {
    const u16x8 kc0 = *(const u16x8*)(kgb + (size_t)(kv0 + sr) * LDP + scc);
    const u16x8 kc1 = *(const u16x8*)(kgb + (size_t)(kv0 + sr + 32) * LDP + scc);
    const u16x8 vc0 = *(const u16x8*)(vgb + (size_t)sr * SEQ + kv0 + scc);
    const u16x8 vc1 = *(const u16x8*)(vgb + (size_t)(sr + 32) * SEQ + kv0 + scc);
    __syncthreads();
    *(u16x8*)&ks[sr * 72 + scc] = kc0;
    *(u16x8*)&ks[(sr + 32) * 72 + scc] = kc1;
    *(u16x8*)&vt[sr * 72 + scc] = vc0;
    *(u16x8*)&vt[(sr + 32) * 72 + scc] = vc1;
    __syncthreads();

    f32x4 sc4[4];
#pragma unroll
    for (int t = 0; t < 4; ++t) {
      const u16* kr = &ks[(t * 16 + l15) * 72 + dfr];
      f32x4 s = {};
      s = mfma16(qf0, ldbf8(kr), s);
      s = mfma16(qf1, ldbf8(kr + 32), s);
      sc4[t] = s * 0.125f;  // 1/sqrt(64)
    }

    float sf[4];
#pragma unroll
    for (int r = 0; r < 4; ++r) {
      float mx = fmaxf(fmaxf(sc4[0][r], sc4[1][r]), fmaxf(sc4[2][r], sc4[3][r]));
      mx = fmaxf(mx, __shfl_xor(mx, 1));
      mx = fmaxf(mx, __shfl_xor(mx, 2));
      mx = fmaxf(mx, __shfl_xor(mx, 4));
      mx = fmaxf(mx, __shfl_xor(mx, 8));
      const float mn = fmaxf(mrun[r], mx);
      const float e0 = __expf(sc4[0][r] - mn);
      const float e1 = __expf(sc4[1][r] - mn);
      const float e2 = __expf(sc4[2][r] - mn);
      const float e3 = __expf(sc4[3][r] - mn);
      u16* pr = &ps[w][(lg * 4 + r) * 72 + l15];
      pr[0]  = f2bf(e0);
      pr[16] = f2bf(e1);
      pr[32] = f2bf(e2);
      pr[48] = f2bf(e3);
      float rs = e0 + e1 + e2 + e3;
      rs += __shfl_xor(rs, 1);
      rs += __shfl_xor(rs, 2);
      rs += __shfl_xor(rs, 4);
      rs += __shfl_xor(rs, 8);
      const float sfr = __expf(mrun[r] - mn);
      lrun[r] = lrun[r] * sfr + rs;
      mrun[r] = mn;
      sf[r] = sfr;
    }
#pragma unroll
    for (int t = 0; t < 4; ++t) {
#pragma unroll
      for (int r = 0; r < 4; ++r) oacc[t][r] *= sf[r];
    }
    const bf16x8 pa0 = ldbf8(&ps[w][l15 * 72 + dfr]);
    const bf16x8 pa1 = ldbf8(&ps[w][l15 * 72 + dfr + 32]);
#pragma unroll
    for (int t = 0; t < 4; ++t) {
      const u16* vr = &vt[(t * 16 + l15) * 72 + dfr];
      oacc[t] = mfma16(pa0, ldbf8(vr), oacc[t]);
      oacc[t] = mfma16(pa1, ldbf8(vr + 32), oacc[t]);
    }
  }

  float inv[4];
#pragma unroll
  for (int r = 0; r < 4; ++r) inv[r] = 1.0f / lrun[r];
#pragma unroll
  for (int t = 0; t < 4; ++t) {
#pragma unroll
    for (int r = 0; r < 4; ++r) {
      const int qq = qB + w * 16 + lg * 4 + r;
      outa[(rb + qq) * DMODEL + h * 64 + t * 16 + l15] = f2bf(oacc[t][r] * inv[r]);
    }
  }
}

extern "C" void kernel_launch(void* const* d_in, const int* in_sizes, int n_in,
                              void* d_out, int out_size, void* d_ws, size_t ws_size,
                              hipStream_t stream) {
  const float* q  = (const float*)d_in[0];
  const float* k  = (const float*)d_in[1];
  const float* v  = (const float*)d_in[2];
  const float* wq = (const float*)d_in[3];
  const float* bq = (const float*)d_in[4];
  const float* wk = (const float*)d_in[5];
  const float* bk = (const float*)d_in[6];
  const float* wv = (const float*)d_in[7];
  const float* bv = (const float*)d_in[8];
  const float* wo = (const float*)d_in[9];
  const float* bo = (const float*)d_in[10];

  const size_t NTOK = (size_t)2 * SEQ;      // 4096 rows
  const size_t NELE = NTOK * DMODEL;        // 4,194,304
  u16* qb    = (u16*)d_ws;
  u16* kb    = qb + NELE;
  u16* vb    = kb + NELE;
  u16* wqkv  = vb + NELE;                   // [3][1024][1024]
  u16* wob   = wqkv + 3 * (size_t)DMODEL * DMODEL;
  u16* projb = wob + (size_t)DMODEL * DMODEL;  // [4096][3072] (Q,K sections used)
  u16* vtb   = projb + NTOK * LDP;          // [32 bh][64 d][2048 s]
  u16* attnb = qb;                          // qb dead after gemm_qk_k -> reuse

  cast_qkv_k<<<dim3(2048, 3), 256, 0, stream>>>(q, k, v, qb, kb, vb);
  cast_w_k<<<dim3(512, 4), 256, 0, stream>>>(wq, wk, wv, wo, wqkv, wob);
  gemm_qk_k<<<dim3(8, 32, 2), 256, 0, stream>>>(qb, kb, wqkv, bq, bk, projb);
  gemm_v_k<<<dim3(8, 32), 256, 0, stream>>>(
      vb, wqkv + 2 * (size_t)DMODEL * DMODEL, bv, vtb);
  attn_k<<<dim3(SEQ / 64, 32), 256, 0, stream>>>(projb, vtb, attnb);
  gemm_o_k<<<dim3(8, 32), 256, 0, stream>>>(attnb, wob, bo, (float*)d_out);
}

// Round 2
// 150.676 us; speedup vs baseline: 1.4116x; 1.4116x over previous
//
#include <hip/hip_runtime.h>

typedef unsigned short u16;
typedef unsigned int u32;
typedef __attribute__((ext_vector_type(8))) unsigned short u16x8;
typedef __attribute__((ext_vector_type(8))) __bf16 bf16x8;
typedef __attribute__((ext_vector_type(4))) float f32x4;

#define SEQ 2048
#define DMODEL 1024
#define LDP 3072
#define MM (DMODEL * DMODEL)

__device__ __forceinline__ u16 f2bf(float f) {
  unsigned u = __builtin_bit_cast(unsigned, f);
  u = (u + 0x7fffu + ((u >> 16) & 1u)) >> 16;
  return (u16)u;
}

__device__ __forceinline__ u32 cvtpk(float lo, float hi) {
  u32 r;
  asm volatile("v_cvt_pk_bf16_f32 %0, %1, %2" : "=v"(r) : "v"(lo), "v"(hi));
  return r;
}

__device__ __forceinline__ bf16x8 ldbf8(const u16* p) {
  return __builtin_bit_cast(bf16x8, *(const u16x8*)p);
}
__device__ __forceinline__ bf16x8 ldbf8c(const char* p) {
  return __builtin_bit_cast(bf16x8, *(const u16x8*)p);
}

__device__ __forceinline__ f32x4 mfma16(bf16x8 a, bf16x8 b, f32x4 c) {
  return __builtin_amdgcn_mfma_f32_16x16x32_bf16(a, b, c, 0, 0, 0);
}

__device__ __forceinline__ void gl16(const void* g, void* l) {
  __builtin_amdgcn_global_load_lds(
      (__attribute__((address_space(1))) void*)(size_t)g,
      (__attribute__((address_space(3))) void*)l, 16, 0, 0);
}

// ----------------- fp32 -> bf16 casts -----------------
__device__ __forceinline__ void cast8(const float* __restrict__ s, u16* __restrict__ d) {
  const size_t i = ((size_t)blockIdx.x * blockDim.x + threadIdx.x) * 8;
  const float4 a = *(const float4*)(s + i);
  const float4 b = *(const float4*)(s + i + 4);
  u16x8 o;
  o[0] = f2bf(a.x); o[1] = f2bf(a.y); o[2] = f2bf(a.z); o[3] = f2bf(a.w);
  o[4] = f2bf(b.x); o[5] = f2bf(b.y); o[6] = f2bf(b.z); o[7] = f2bf(b.w);
  *(u16x8*)(d + i) = o;
}

__global__ void cast_qkv_k(const float* __restrict__ q, const float* __restrict__ k,
                           const float* __restrict__ v, u16* __restrict__ dq,
                           u16* __restrict__ dk, u16* __restrict__ dv) {
  const int z = blockIdx.y;
  cast8(z == 0 ? q : z == 1 ? k : v, z == 0 ? dq : z == 1 ? dk : dv);
}

__global__ void cast_w_k(const float* __restrict__ wq, const float* __restrict__ wk,
                         const float* __restrict__ wv, const float* __restrict__ wo,
                         u16* __restrict__ wqkv, u16* __restrict__ wob) {
  const int z = blockIdx.y;
  const float* s = z == 0 ? wq : z == 1 ? wk : z == 2 ? wv : wo;
  u16* d = z < 3 ? wqkv + (size_t)z * MM : wob;
  cast8(s, d);
}

// ----------------- GEMM: C = A @ B^T + bias (m97 structure) -----------------
// A:[M,K] bf16 row-major; B:[N,K] bf16 row-major. BK=32, 128x128 tile,
// global_load_lds width-16 staging into linear [128][32] LDS (64B rows).
// OMODE 0: fp32 out row-major. 1: bf16 out row-major (+ncol0). 2: bf16 out
// scattered as vT[b,h,d,s].
template <int OMODE>
__device__ __forceinline__ void gemm_bt_body(const u16* __restrict__ A,
                                             const u16* __restrict__ Bw,
                                             const float* __restrict__ bias,
                                             void* __restrict__ Cv, const int K,
                                             const int ldc, const int ncol0) {
  __shared__ u16 As[128 * 32];
  __shared__ u16 Bs[128 * 32];
  const int tid = threadIdx.x;
  const int lane = tid & 63;
  const int w = tid >> 6;
  const int m0 = blockIdx.y * 128;
  const int n0 = blockIdx.x * 128;
  const int l15 = lane & 15;
  const int lg = lane >> 4;

  f32x4 acc[4][4] = {};

  const int arow = (w >> 1) * 64 + l15;
  const int brow = (w & 1) * 64 + l15;
  const int kfb = lg * 16;  // byte offset into 64B k-row

  // staging: wave w stages rows [32w, 32w+32) of both tiles, 2 chunks each.
  const int strow = w * 32 + (lane >> 2);
  const u16* Ag = A + (size_t)(m0 + strow) * K + (lane & 3) * 8;
  const u16* Bg = Bw + (size_t)(n0 + strow) * K + (lane & 3) * 8;
  const size_t rstep = (size_t)16 * K;
  char* AsL0 = (char*)As + w * 32 * 64;
  char* AsL1 = AsL0 + 16 * 64;
  char* BsL0 = (char*)Bs + w * 32 * 64;
  char* BsL1 = BsL0 + 16 * 64;

  for (int k0 = 0; k0 < K; k0 += 32) {
    __syncthreads();  // prior iter's LDS reads done
    gl16(Ag + k0, AsL0);
    gl16(Ag + k0 + rstep, AsL1);
    gl16(Bg + k0, BsL0);
    gl16(Bg + k0 + rstep, BsL1);
    __syncthreads();  // barrier drains vmcnt -> staged data visible
    bf16x8 af[4], bfv[4];
#pragma unroll
    for (int t = 0; t < 4; ++t) {
      af[t] = ldbf8c((char*)As + (arow + t * 16) * 64 + kfb);
      bfv[t] = ldbf8c((char*)Bs + (brow + t * 16) * 64 + kfb);
    }
    __builtin_amdgcn_s_setprio(1);
#pragma unroll
    for (int i = 0; i < 4; ++i)
#pragma unroll
      for (int j = 0; j < 4; ++j) acc[i][j] = mfma16(af[i], bfv[j], acc[i][j]);
    __builtin_amdgcn_s_setprio(0);
  }

  const int mrow = (w >> 1) * 64 + lg * 4;
  const int ncol = (w & 1) * 64 + l15;
#pragma unroll
  for (int j = 0; j < 4; ++j) {
    const int gn = n0 + ncol + j * 16;
    const float bia = bias[gn];
#pragma unroll
    for (int i = 0; i < 4; ++i) {
      const int gmb = m0 + mrow + i * 16;
#pragma unroll
      for (int r = 0; r < 4; ++r) {
        const float val = acc[i][j][r] + bia;
        const int gm = gmb + r;
        if (OMODE == 0) {
          ((float*)Cv)[(size_t)gm * ldc + gn] = val;
        } else if (OMODE == 1) {
          ((u16*)Cv)[(size_t)gm * ldc + ncol0 + gn] = f2bf(val);
        } else {
          const int bb = gm >> 11, ss = gm & 2047;
          const int hh = gn >> 6, dd = gn & 63;
          ((u16*)Cv)[(((size_t)(bb * 16 + hh) * 64 + dd) << 11) + ss] = f2bf(val);
        }
      }
    }
  }
}

__global__ __launch_bounds__(256, 3) void gemm_qkv_k(
    const u16* __restrict__ qb, const u16* __restrict__ kb,
    const u16* __restrict__ vb, const u16* __restrict__ wqkv,
    const float* __restrict__ bq, const float* __restrict__ bk,
    const float* __restrict__ bv, u16* __restrict__ proj, u16* __restrict__ vtb) {
  const int z = blockIdx.z;
  if (z == 2)
    gemm_bt_body<2>(vb, wqkv + 2 * (size_t)MM, bv, vtb, DMODEL, 0, 0);
  else
    gemm_bt_body<1>(z == 0 ? qb : kb, wqkv + (size_t)z * MM, z == 0 ? bq : bk,
                    proj, DMODEL, LDP, z * DMODEL);
}

__global__ __launch_bounds__(256, 3) void gemm_o_k(const u16* __restrict__ attnb,
                                                   const u16* __restrict__ wob,
                                                   const float* __restrict__ bo,
                                                   float* __restrict__ out) {
  gemm_bt_body<0>(attnb, wob, bo, out, DMODEL, DMODEL, 0);
}

// ----------------- flash attention (swapped-operand, 1 barrier/iter) ------
// grid (SEQ/64, B*H); 4 waves; wave w owns Q rows qB+w*16..+15 (q = lane&15).
// QK^T = mfma(K, Q) -> lane holds S[kv=t*16+lg*4+r][q=l15]  (in-lane softmax)
// PV   = mfma(V^T, P) -> lane holds O^T[d=t*16+lg*4+r][q=l15]
__global__ __launch_bounds__(256, 4) void attn_k(const u16* __restrict__ proj,
                                                 const u16* __restrict__ vtb,
                                                 u16* __restrict__ outa) {
  __shared__ u16 ks[2][64 * 64];   // [kv][d], XOR-swizzled, 8KB each
  __shared__ u16 vs[2][64 * 64];   // [d][kv], XOR-swizzled
  __shared__ u16 ps[4][16 * 64];   // per-wave P [q][kv], XOR-swizzled
  const int tid = threadIdx.x;
  const int lane = tid & 63;
  const int w = tid >> 6;
  const int qB = blockIdx.x * 64;
  const int bh = blockIdx.y;
  const size_t rb = (size_t)(bh >> 4) * SEQ;
  const int h = bh & 15;
  const int l15 = lane & 15;
  const int lg = lane >> 4;
  const int sw = (l15 & 7) << 4;                  // read-side row swizzle
  const int c0 = (lg * 16) ^ sw;                  // k/kv bytes 0..31 els
  const int c1 = (lg * 16 + 64) ^ sw;             // els 32..63
  const int rowb = l15 * 128;

  // Q B-fragments: Q[q=l15][d=lg*8+j], halves d / d+32
  const u16* qp = proj + (rb + qB + w * 16 + l15) * LDP + h * 64 + lg * 8;
  const bf16x8 qf0 = ldbf8(qp);
  const bf16x8 qf1 = ldbf8(qp + 32);

  // staging addressing: thread -> row tid>>2, 32B at col (tid&3)*32 bytes
  const int srow = tid >> 2;
  const int scel = (tid & 3) * 16;
  const int stz0 = srow * 128 + (((tid & 3) * 32) ^ ((srow & 7) << 4));
  const int stz1 = srow * 128 + ((((tid & 3) * 32) + 16) ^ ((srow & 7) << 4));
  const u16* kg = proj + rb * LDP + DMODEL + h * 64;  // K rows, stride LDP
  const u16* vg = vtb + (size_t)bh * 64 * SEQ;        // V^T rows [d][s]

  u16x8 ka0, ka1, va0, va1;
  {
    const u16* kr = kg + (size_t)srow * LDP + scel;
    ka0 = *(const u16x8*)kr;
    ka1 = *(const u16x8*)(kr + 8);
    const u16* vr = vg + (size_t)srow * SEQ + scel;
    va0 = *(const u16x8*)vr;
    va1 = *(const u16x8*)(vr + 8);
  }

  f32x4 oacc[4] = {};
  float mrun = -3.0e38f, lrun = 0.f;
  char* const pw = (char*)ps[w];
  int p = 0;

  for (int kv0 = 0; kv0 < SEQ; kv0 += 64) {
    // (1) write staged regs -> buf p
    {
      char* kd = (char*)ks[p];
      char* vd = (char*)vs[p];
      *(u16x8*)(kd + stz0) = ka0;
      *(u16x8*)(kd + stz1) = ka1;
      *(u16x8*)(vd + stz0) = va0;
      *(u16x8*)(vd + stz1) = va1;
    }
    __syncthreads();  // (2) single barrier per iter
    // (3) prefetch next tile -> regs (overlaps compute below)
    if (kv0 + 64 < SEQ) {
      const u16* kr = kg + (size_t)(kv0 + 64 + srow) * LDP + scel;
      ka0 = *(const u16x8*)kr;
      ka1 = *(const u16x8*)(kr + 8);
      const u16* vr = vg + (size_t)srow * SEQ + kv0 + 64 + scel;
      va0 = *(const u16x8*)vr;
      va1 = *(const u16x8*)(vr + 8);
    }
    // (4) compute on buf p
    const char* kb = (const char*)ks[p];
    f32x4 st[4];
    __builtin_amdgcn_s_setprio(1);
#pragma unroll
    for (int t = 0; t < 4; ++t) {
      const bf16x8 k0 = ldbf8c(kb + t * 2048 + rowb + c0);
      const bf16x8 k1 = ldbf8c(kb + t * 2048 + rowb + c1);
      f32x4 s = {};
      s = mfma16(k0, qf0, s);
      s = mfma16(k1, qf1, s);
      st[t] = s * 0.125f;  // 1/sqrt(64)
    }
    __builtin_amdgcn_s_setprio(0);

    // in-lane softmax over the 16 held kv-scores, cross-lg via 2 shfls
    float mx0 = fmaxf(fmaxf(st[0][0], st[0][1]), fmaxf(st[0][2], st[0][3]));
    float mx1 = fmaxf(fmaxf(st[1][0], st[1][1]), fmaxf(st[1][2], st[1][3]));
    float mx2 = fmaxf(fmaxf(st[2][0], st[2][1]), fmaxf(st[2][2], st[2][3]));
    float mx3 = fmaxf(fmaxf(st[3][0], st[3][1]), fmaxf(st[3][2], st[3][3]));
    float mx = fmaxf(fmaxf(mx0, mx1), fmaxf(mx2, mx3));
    mx = fmaxf(mx, __shfl_xor(mx, 16));
    mx = fmaxf(mx, __shfl_xor(mx, 32));
    const float mn = fmaxf(mrun, mx);
    const float sf = __expf(mrun - mn);
    mrun = mn;
    float rs = 0.f;
#pragma unroll
    for (int t = 0; t < 4; ++t) {
      const float e0 = __expf(st[t][0] - mn);
      const float e1 = __expf(st[t][1] - mn);
      const float e2 = __expf(st[t][2] - mn);
      const float e3 = __expf(st[t][3] - mn);
      rs += (e0 + e1) + (e2 + e3);
      *(u32*)(pw + rowb + ((t * 32 + lg * 8) ^ sw)) = cvtpk(e0, e1);
      *(u32*)(pw + rowb + ((t * 32 + lg * 8 + 4) ^ sw)) = cvtpk(e2, e3);
    }
    rs += __shfl_xor(rs, 16);
    rs += __shfl_xor(rs, 32);
    lrun = lrun * sf + rs;
#pragma unroll
    for (int t = 0; t < 4; ++t) {
#pragma unroll
      for (int r = 0; r < 4; ++r) oacc[t][r] *= sf;
    }

    const bf16x8 pb0 = ldbf8c(pw + rowb + c0);
    const bf16x8 pb1 = ldbf8c(pw + rowb + c1);
    const char* vbp = (const char*)vs[p];
    __builtin_amdgcn_s_setprio(1);
#pragma unroll
    for (int t = 0; t < 4; ++t) {
      const bf16x8 v0 = ldbf8c(vbp + t * 2048 + rowb + c0);
      const bf16x8 v1 = ldbf8c(vbp + t * 2048 + rowb + c1);
      oacc[t] = mfma16(v0, pb0, oacc[t]);
      oacc[t] = mfma16(v1, pb1, oacc[t]);
    }
    __builtin_amdgcn_s_setprio(0);
    p ^= 1;
  }

  const float invl = 1.0f / lrun;
  u16* orow = outa + (rb + qB + w * 16 + l15) * DMODEL + h * 64;
#pragma unroll
  for (int t = 0; t < 4; ++t) {
    const u32 p01 = cvtpk(oacc[t][0] * invl, oacc[t][1] * invl);
    const u32 p23 = cvtpk(oacc[t][2] * invl, oacc[t][3] * invl);
    *(u32*)((char*)orow + (t * 16 + lg * 4) * 2) = p01;
    *(u32*)((char*)orow + (t * 16 + lg * 4 + 2) * 2) = p23;
  }
}

extern "C" void kernel_launch(void* const* d_in, const int* in_sizes, int n_in,
                              void* d_out, int out_size, void* d_ws, size_t ws_size,
                              hipStream_t stream) {
  const float* q  = (const float*)d_in[0];
  const float* k  = (const float*)d_in[1];
  const float* v  = (const float*)d_in[2];
  const float* wq = (const float*)d_in[3];
  const float* bq = (const float*)d_in[4];
  const float* wk = (const float*)d_in[5];
  const float* bk = (const float*)d_in[6];
  const float* wv = (const float*)d_in[7];
  const float* bv = (const float*)d_in[8];
  const float* wo = (const float*)d_in[9];
  const float* bo = (const float*)d_in[10];

  const size_t NTOK = (size_t)2 * SEQ;      // 4096 rows
  const size_t NELE = NTOK * DMODEL;        // 4,194,304
  u16* qb    = (u16*)d_ws;
  u16* kb    = qb + NELE;
  u16* vb    = kb + NELE;
  u16* wqkv  = vb + NELE;                   // [3][1024][1024]
  u16* wob   = wqkv + 3 * (size_t)MM;
  u16* projb = wob + (size_t)MM;            // [4096][3072] (Q,K sections used)
  u16* vtb   = projb + NTOK * LDP;          // [32 bh][64 d][2048 s]
  u16* attnb = qb;                          // qb dead after projections -> reuse

  cast_qkv_k<<<dim3(2048, 3), 256, 0, stream>>>(q, k, v, qb, kb, vb);
  cast_w_k<<<dim3(512, 4), 256, 0, stream>>>(wq, wk, wv, wo, wqkv, wob);
  gemm_qkv_k<<<dim3(8, 32, 3), 256, 0, stream>>>(qb, kb, vb, wqkv, bq, bk, bv,
                                                 projb, vtb);
  attn_k<<<dim3(SEQ / 64, 32), 256, 0, stream>>>(projb, vtb, attnb);
  gemm_o_k<<<dim3(8, 32), 256, 0, stream>>>(attnb, wob, bo, (float*)d_out);
}

// Round 3
// 141.690 us; speedup vs baseline: 1.5012x; 1.0634x over previous
//
#include <hip/hip_runtime.h>

typedef unsigned short u16;
typedef unsigned int u32;
typedef __attribute__((ext_vector_type(4))) unsigned short u16x4;
typedef __attribute__((ext_vector_type(8))) unsigned short u16x8;
typedef __attribute__((ext_vector_type(8))) __bf16 bf16x8;
typedef __attribute__((ext_vector_type(4))) float f32x4;

#define SEQ 2048
#define DMODEL 1024
#define LDP 3072
#define MM (DMODEL * DMODEL)

__device__ __forceinline__ u16 f2bf(float f) {
  unsigned u = __builtin_bit_cast(unsigned, f);
  u = (u + 0x7fffu + ((u >> 16) & 1u)) >> 16;
  return (u16)u;
}

__device__ __forceinline__ u32 cvtpk(float lo, float hi) {
  u32 r;
  asm volatile("v_cvt_pk_bf16_f32 %0, %1, %2" : "=v"(r) : "v"(lo), "v"(hi));
  return r;
}

__device__ __forceinline__ float fexp2(float x) {
#if __has_builtin(__builtin_amdgcn_exp2f)
  return __builtin_amdgcn_exp2f(x);
#else
  return exp2f(x);
#endif
}

__device__ __forceinline__ bf16x8 ldbf8(const u16* p) {
  return __builtin_bit_cast(bf16x8, *(const u16x8*)p);
}
__device__ __forceinline__ bf16x8 ldbf8c(const char* p) {
  return __builtin_bit_cast(bf16x8, *(const u16x8*)p);
}

__device__ __forceinline__ f32x4 mfma16(bf16x8 a, bf16x8 b, f32x4 c) {
  return __builtin_amdgcn_mfma_f32_16x16x32_bf16(a, b, c, 0, 0, 0);
}

__device__ __forceinline__ void gl16(const void* g, void* l) {
  __builtin_amdgcn_global_load_lds(
      (__attribute__((address_space(1))) void*)(size_t)g,
      (__attribute__((address_space(3))) void*)l, 16, 0, 0);
}

// ----------------- fp32 -> bf16 casts -----------------
__device__ __forceinline__ void cast8(const float* __restrict__ s, u16* __restrict__ d) {
  const size_t i = ((size_t)blockIdx.x * blockDim.x + threadIdx.x) * 8;
  const float4 a = *(const float4*)(s + i);
  const float4 b = *(const float4*)(s + i + 4);
  u16x8 o;
  o[0] = f2bf(a.x); o[1] = f2bf(a.y); o[2] = f2bf(a.z); o[3] = f2bf(a.w);
  o[4] = f2bf(b.x); o[5] = f2bf(b.y); o[6] = f2bf(b.z); o[7] = f2bf(b.w);
  *(u16x8*)(d + i) = o;
}

__global__ void cast_qkv_k(const float* __restrict__ q, const float* __restrict__ k,
                           const float* __restrict__ v, u16* __restrict__ dq,
                           u16* __restrict__ dk, u16* __restrict__ dv) {
  const int z = blockIdx.y;
  cast8(z == 0 ? q : z == 1 ? k : v, z == 0 ? dq : z == 1 ? dk : dv);
}

__global__ void cast_w_k(const float* __restrict__ wq, const float* __restrict__ wk,
                         const float* __restrict__ wv, const float* __restrict__ wo,
                         u16* __restrict__ wqkv, u16* __restrict__ wob) {
  const int z = blockIdx.y;
  const float* s = z == 0 ? wq : z == 1 ? wk : z == 2 ? wv : wo;
  u16* d = z < 3 ? wqkv + (size_t)z * MM : wob;
  cast8(s, d);
}

// ----------------- GEMM: C = A @ B^T + bias (m97 structure) -----------------
// A:[M,K] bf16 row-major; B:[N,K] bf16 row-major. BK=32, 128x128 tile,
// global_load_lds width-16 staging into linear [128][32] LDS (64B rows).
template <int OMODE>
__device__ __forceinline__ void gemm_bt_body(const u16* __restrict__ A,
                                             const u16* __restrict__ Bw,
                                             const float* __restrict__ bias,
                                             void* __restrict__ Cv, const int K,
                                             const int ldc, const int ncol0,
                                             const int m0, const int n0) {
  __shared__ u16 As[128 * 32];
  __shared__ u16 Bs[128 * 32];
  const int tid = threadIdx.x;
  const int lane = tid & 63;
  const int w = tid >> 6;
  const int l15 = lane & 15;
  const int lg = lane >> 4;

  f32x4 acc[4][4] = {};

  const int arow = (w >> 1) * 64 + l15;
  const int brow = (w & 1) * 64 + l15;
  const int kfb = lg * 16;  // byte offset into 64B k-row

  const int strow = w * 32 + (lane >> 2);
  const u16* Ag = A + (size_t)(m0 + strow) * K + (lane & 3) * 8;
  const u16* Bg = Bw + (size_t)(n0 + strow) * K + (lane & 3) * 8;
  const size_t rstep = (size_t)16 * K;
  char* AsL0 = (char*)As + w * 32 * 64;
  char* AsL1 = AsL0 + 16 * 64;
  char* BsL0 = (char*)Bs + w * 32 * 64;
  char* BsL1 = BsL0 + 16 * 64;

  for (int k0 = 0; k0 < K; k0 += 32) {
    __syncthreads();  // prior iter's LDS reads done
    gl16(Ag + k0, AsL0);
    gl16(Ag + k0 + rstep, AsL1);
    gl16(Bg + k0, BsL0);
    gl16(Bg + k0 + rstep, BsL1);
    __syncthreads();  // barrier drains vmcnt -> staged data visible
    bf16x8 af[4], bfv[4];
#pragma unroll
    for (int t = 0; t < 4; ++t) {
      af[t] = ldbf8c((char*)As + (arow + t * 16) * 64 + kfb);
      bfv[t] = ldbf8c((char*)Bs + (brow + t * 16) * 64 + kfb);
    }
    __builtin_amdgcn_s_setprio(1);
#pragma unroll
    for (int i = 0; i < 4; ++i)
#pragma unroll
      for (int j = 0; j < 4; ++j) acc[i][j] = mfma16(af[i], bfv[j], acc[i][j]);
    __builtin_amdgcn_s_setprio(0);
  }

  const int mrow = (w >> 1) * 64 + lg * 4;
  const int ncol = (w & 1) * 64 + l15;
#pragma unroll
  for (int j = 0; j < 4; ++j) {
    const int gn = n0 + ncol + j * 16;
    const float bia = bias[gn];
#pragma unroll
    for (int i = 0; i < 4; ++i) {
      const int gmb = m0 + mrow + i * 16;
#pragma unroll
      for (int r = 0; r < 4; ++r) {
        const float val = acc[i][j][r] + bia;
        const int gm = gmb + r;
        if (OMODE == 0) {
          ((float*)Cv)[(size_t)gm * ldc + gn] = val;
        } else if (OMODE == 1) {
          ((u16*)Cv)[(size_t)gm * ldc + ncol0 + gn] = f2bf(val);
        } else {
          const int bb = gm >> 11, ss = gm & 2047;
          const int hh = gn >> 6, dd = gn & 63;
          ((u16*)Cv)[(((size_t)(bb * 16 + hh) * 64 + dd) << 11) + ss] = f2bf(val);
        }
      }
    }
  }
}

// XCD-chunked QKV projections. 768 blocks; xcd = b&7 (HW round-robin).
// Per XCD: 96 slots = 3 z-phases x (4 M-panels x 8 N-tiles) -> per-phase
// working set = 4 A-panels (1MB) + full weight (2MB) fits 4MB L2.
__global__ __launch_bounds__(256, 3) void gemm_qkv_k(
    const u16* __restrict__ qb, const u16* __restrict__ kb,
    const u16* __restrict__ vb, const u16* __restrict__ wqkv,
    const float* __restrict__ bq, const float* __restrict__ bk,
    const float* __restrict__ bv, u16* __restrict__ proj, u16* __restrict__ vtb) {
  const int b = blockIdx.x;
  const int xcd = b & 7;
  const int i = b >> 3;          // 0..95
  const int z = i >> 5;          // 0,1,2 sequential per XCD
  const int j = i & 31;
  const int m0 = (xcd * 4 + (j >> 3)) * 128;
  const int n0 = (j & 7) * 128;
  if (z == 2)
    gemm_bt_body<2>(vb, wqkv + 2 * (size_t)MM, bv, vtb, DMODEL, 0, 0, m0, n0);
  else
    gemm_bt_body<1>(z == 0 ? qb : kb, wqkv + (size_t)z * MM, z == 0 ? bq : bk,
                    proj, DMODEL, LDP, z * DMODEL, m0, n0);
}

__global__ __launch_bounds__(256, 3) void gemm_o_k(const u16* __restrict__ attnb,
                                                   const u16* __restrict__ wob,
                                                   const float* __restrict__ bo,
                                                   float* __restrict__ out) {
  const int b = blockIdx.x;
  const int xcd = b & 7;
  const int i = b >> 3;          // 0..31
  const int m0 = (xcd * 4 + (i >> 3)) * 128;
  const int n0 = (i & 7) * 128;
  gemm_bt_body<0>(attnb, wob, bo, out, DMODEL, DMODEL, 0, m0, n0);
}

// ----------------- flash attention (swapped-operand, in-register P) ------
// 1024 blocks; xcd = b&7; 4 heads per XCD (K/V stay in that XCD's L2).
// QK^T = mfma(K, Q) -> lane holds S[kv=t*16+lg*4+r][q=l15]
// P packed in-register via cvt_pk; PV uses k-permutation pi(lg,j) =
// (j>=4)*16 + 4*lg + (j&3) on BOTH operands (V read as 2x ds_read_b64).
__global__ __launch_bounds__(256, 4) void attn_k(const u16* __restrict__ proj,
                                                 const u16* __restrict__ vtb,
                                                 u16* __restrict__ outa) {
  __shared__ u16 ks[2][64 * 64];   // [kv][d], XOR-swizzled, 8KB each
  __shared__ u16 vs[2][64 * 64];   // [d][kv], XOR-swizzled
  const int b = blockIdx.x;
  const int slot = b >> 3;
  const int bh = (b & 7) * 4 + (slot >> 5);
  const int qB = (slot & 31) * 64;
  const int tid = threadIdx.x;
  const int lane = tid & 63;
  const int w = tid >> 6;
  const size_t rb = (size_t)(bh >> 4) * SEQ;
  const int h = bh & 15;
  const int l15 = lane & 15;
  const int lg = lane >> 4;
  const int sw = (l15 & 7) << 4;                  // read-side row swizzle
  const int c0 = (lg * 16) ^ sw;                  // K bytes, els 0..31
  const int c1 = (lg * 16 + 64) ^ sw;             // els 32..63
  const int rowb = l15 * 128;

  // Q B-fragments: Q[q=l15][d=lg*8+j], halves d / d+32
  const u16* qp = proj + (rb + qB + w * 16 + l15) * LDP + h * 64 + lg * 8;
  const bf16x8 qf0 = ldbf8(qp);
  const bf16x8 qf1 = ldbf8(qp + 32);

  const int srow = tid >> 2;
  const int scel = (tid & 3) * 16;
  const int stz0 = srow * 128 + (((tid & 3) * 32) ^ ((srow & 7) << 4));
  const int stz1 = srow * 128 + ((((tid & 3) * 32) + 16) ^ ((srow & 7) << 4));
  const u16* kg = proj + rb * LDP + DMODEL + h * 64;  // K rows, stride LDP
  const u16* vg = vtb + (size_t)bh * 64 * SEQ;        // V^T rows [d][s]

  u16x8 ka0, ka1, va0, va1;
  {
    const u16* kr = kg + (size_t)srow * LDP + scel;
    ka0 = *(const u16x8*)kr;
    ka1 = *(const u16x8*)(kr + 8);
    const u16* vr = vg + (size_t)srow * SEQ + scel;
    va0 = *(const u16x8*)vr;
    va1 = *(const u16x8*)(vr + 8);
  }

  f32x4 oacc[4] = {};
  float mrun = -3.0e38f, lrun = 0.f;
  int p = 0;

  for (int kv0 = 0; kv0 < SEQ; kv0 += 64) {
    {
      char* kd = (char*)ks[p];
      char* vd = (char*)vs[p];
      *(u16x8*)(kd + stz0) = ka0;
      *(u16x8*)(kd + stz1) = ka1;
      *(u16x8*)(vd + stz0) = va0;
      *(u16x8*)(vd + stz1) = va1;
    }
    __syncthreads();  // single barrier per iter
    if (kv0 + 64 < SEQ) {  // prefetch next tile -> regs
      const u16* kr = kg + (size_t)(kv0 + 64 + srow) * LDP + scel;
      ka0 = *(const u16x8*)kr;
      ka1 = *(const u16x8*)(kr + 8);
      const u16* vr = vg + (size_t)srow * SEQ + kv0 + 64 + scel;
      va0 = *(const u16x8*)vr;
      va1 = *(const u16x8*)(vr + 8);
    }
    // QK^T on buf p (scores scaled into log2 domain)
    const char* kb = (const char*)ks[p];
    f32x4 st[4];
    __builtin_amdgcn_s_setprio(1);
#pragma unroll
    for (int t = 0; t < 4; ++t) {
      const bf16x8 k0 = ldbf8c(kb + t * 2048 + rowb + c0);
      const bf16x8 k1 = ldbf8c(kb + t * 2048 + rowb + c1);
      f32x4 s = {};
      s = mfma16(k0, qf0, s);
      s = mfma16(k1, qf1, s);
      st[t] = s * 0.18033688f;  // (1/8) * log2(e)
    }
    __builtin_amdgcn_s_setprio(0);

    // tile max (log2 domain), cross-lg via 2 shfls
    float mx0 = fmaxf(fmaxf(st[0][0], st[0][1]), fmaxf(st[0][2], st[0][3]));
    float mx1 = fmaxf(fmaxf(st[1][0], st[1][1]), fmaxf(st[1][2], st[1][3]));
    float mx2 = fmaxf(fmaxf(st[2][0], st[2][1]), fmaxf(st[2][2], st[2][3]));
    float mx3 = fmaxf(fmaxf(st[3][0], st[3][1]), fmaxf(st[3][2], st[3][3]));
    float mx = fmaxf(fmaxf(mx0, mx1), fmaxf(mx2, mx3));
    mx = fmaxf(mx, __shfl_xor(mx, 16));
    mx = fmaxf(mx, __shfl_xor(mx, 32));
    // defer-max (T13): only rescale if some q-row grew past THR=8/ln2
    if (!__all(mx <= mrun + 11.5416f)) {
      const float mn = fmaxf(mrun, mx);
      const float sf = fexp2(mrun - mn);
      mrun = mn;
      lrun *= sf;
#pragma unroll
      for (int t = 0; t < 4; ++t)
#pragma unroll
        for (int r = 0; r < 4; ++r) oacc[t][r] *= sf;
    }
    float rs = 0.f;
    u32 pku[4][2];
#pragma unroll
    for (int t = 0; t < 4; ++t) {
      const float e0 = fexp2(st[t][0] - mrun);
      const float e1 = fexp2(st[t][1] - mrun);
      const float e2 = fexp2(st[t][2] - mrun);
      const float e3 = fexp2(st[t][3] - mrun);
      rs += (e0 + e1) + (e2 + e3);
      pku[t][0] = cvtpk(e0, e1);
      pku[t][1] = cvtpk(e2, e3);
    }
    rs += __shfl_xor(rs, 16);
    rs += __shfl_xor(rs, 32);
    lrun += rs;

    // P B-fragments (zero-exchange: pi-permuted k order)
    u16x8 pb0, pb1;
    ((u32*)&pb0)[0] = pku[0][0]; ((u32*)&pb0)[1] = pku[0][1];
    ((u32*)&pb0)[2] = pku[1][0]; ((u32*)&pb0)[3] = pku[1][1];
    ((u32*)&pb1)[0] = pku[2][0]; ((u32*)&pb1)[1] = pku[2][1];
    ((u32*)&pb1)[2] = pku[3][0]; ((u32*)&pb1)[3] = pku[3][1];
    const bf16x8 pf0 = __builtin_bit_cast(bf16x8, pb0);
    const bf16x8 pf1 = __builtin_bit_cast(bf16x8, pb1);

    // PV: A-frag element j = V^T[d][pi(lg,j)] -> 2x ds_read_b64 per half
    const char* vbp = (const char*)vs[p];
    const int vo0 = (8 * lg) ^ sw;          // kv 4lg..4lg+3
    __builtin_amdgcn_s_setprio(1);
#pragma unroll
    for (int dt = 0; dt < 4; ++dt) {
      const char* vrow = vbp + (dt * 16 + l15) * 128;
      u16x8 vf0, vf1;
      *(u16x4*)&vf0       = *(const u16x4*)(vrow + vo0);
      *((u16x4*)&vf0 + 1) = *(const u16x4*)(vrow + (vo0 ^ 32));
      *(u16x4*)&vf1       = *(const u16x4*)(vrow + (vo0 ^ 64));
      *((u16x4*)&vf1 + 1) = *(const u16x4*)(vrow + (vo0 ^ 96));
      oacc[dt] = mfma16(__builtin_bit_cast(bf16x8, vf0), pf0, oacc[dt]);
      oacc[dt] = mfma16(__builtin_bit_cast(bf16x8, vf1), pf1, oacc[dt]);
    }
    __builtin_amdgcn_s_setprio(0);
    p ^= 1;
  }

  const float invl = 1.0f / lrun;
  u16* orow = outa + (rb + qB + w * 16 + l15) * DMODEL + h * 64;
#pragma unroll
  for (int t = 0; t < 4; ++t) {
    const u32 p01 = cvtpk(oacc[t][0] * invl, oacc[t][1] * invl);
    const u32 p23 = cvtpk(oacc[t][2] * invl, oacc[t][3] * invl);
    *(u32*)((char*)orow + (t * 16 + lg * 4) * 2) = p01;
    *(u32*)((char*)orow + (t * 16 + lg * 4 + 2) * 2) = p23;
  }
}

extern "C" void kernel_launch(void* const* d_in, const int* in_sizes, int n_in,
                              void* d_out, int out_size, void* d_ws, size_t ws_size,
                              hipStream_t stream) {
  const float* q  = (const float*)d_in[0];
  const float* k  = (const float*)d_in[1];
  const float* v  = (const float*)d_in[2];
  const float* wq = (const float*)d_in[3];
  const float* bq = (const float*)d_in[4];
  const float* wk = (const float*)d_in[5];
  const float* bk = (const float*)d_in[6];
  const float* wv = (const float*)d_in[7];
  const float* bv = (const float*)d_in[8];
  const float* wo = (const float*)d_in[9];
  const float* bo = (const float*)d_in[10];

  const size_t NTOK = (size_t)2 * SEQ;      // 4096 rows
  const size_t NELE = NTOK * DMODEL;        // 4,194,304
  u16* qb    = (u16*)d_ws;
  u16* kb    = qb + NELE;
  u16* vb    = kb + NELE;
  u16* wqkv  = vb + NELE;                   // [3][1024][1024]
  u16* wob   = wqkv + 3 * (size_t)MM;
  u16* projb = wob + (size_t)MM;            // [4096][3072] (Q,K sections used)
  u16* vtb   = projb + NTOK * LDP;          // [32 bh][64 d][2048 s]
  u16* attnb = qb;                          // qb dead after projections -> reuse

  cast_qkv_k<<<dim3(2048, 3), 256, 0, stream>>>(q, k, v, qb, kb, vb);
  cast_w_k<<<dim3(512, 4), 256, 0, stream>>>(wq, wk, wv, wo, wqkv, wob);
  gemm_qkv_k<<<768, 256, 0, stream>>>(qb, kb, vb, wqkv, bq, bk, bv, projb, vtb);
  attn_k<<<1024, 256, 0, stream>>>(projb, vtb, attnb);
  gemm_o_k<<<256, 256, 0, stream>>>(attnb, wob, bo, (float*)d_out);
}

// Round 5
// 127.347 us; speedup vs baseline: 1.6702x; 1.1126x over previous
//
#include <hip/hip_runtime.h>

typedef unsigned short u16;
typedef unsigned int u32;
typedef __attribute__((ext_vector_type(4))) unsigned short u16x4;
typedef __attribute__((ext_vector_type(8))) unsigned short u16x8;
typedef __attribute__((ext_vector_type(8))) __bf16 bf16x8;
typedef __attribute__((ext_vector_type(4))) float f32x4;
typedef __attribute__((ext_vector_type(16))) float f32x16;

#define SEQ 2048
#define DMODEL 1024
#define LDP 3072
#define MM (DMODEL * DMODEL)
#define SC 0.18033688f  // (1/8) * log2(e)

__device__ __forceinline__ u16 f2bf(float f) {
  unsigned u = __builtin_bit_cast(unsigned, f);
  u = (u + 0x7fffu + ((u >> 16) & 1u)) >> 16;
  return (u16)u;
}

__device__ __forceinline__ u32 cvtpk(float lo, float hi) {
  u32 r;
  asm volatile("v_cvt_pk_bf16_f32 %0, %1, %2" : "=v"(r) : "v"(lo), "v"(hi));
  return r;
}

__device__ __forceinline__ float fexp2(float x) {
#if __has_builtin(__builtin_amdgcn_exp2f)
  return __builtin_amdgcn_exp2f(x);
#else
  return exp2f(x);
#endif
}

__device__ __forceinline__ bf16x8 ldbf8(const u16* p) {
  return __builtin_bit_cast(bf16x8, *(const u16x8*)p);
}
__device__ __forceinline__ bf16x8 ldbf8c(const char* p) {
  return __builtin_bit_cast(bf16x8, *(const u16x8*)p);
}

__device__ __forceinline__ f32x4 mfma16(bf16x8 a, bf16x8 b, f32x4 c) {
  return __builtin_amdgcn_mfma_f32_16x16x32_bf16(a, b, c, 0, 0, 0);
}
__device__ __forceinline__ f32x16 mfma32(bf16x8 a, bf16x8 b, f32x16 c) {
  return __builtin_amdgcn_mfma_f32_32x32x16_bf16(a, b, c, 0, 0, 0);
}

__device__ __forceinline__ void gl16(const void* g, void* l) {
  __builtin_amdgcn_global_load_lds(
      (__attribute__((address_space(1))) void*)(size_t)g,
      (__attribute__((address_space(3))) void*)l, 16, 0, 0);
}

// ----------------- fp32 -> bf16 casts -----------------
__device__ __forceinline__ void cast8(const float* __restrict__ s, u16* __restrict__ d) {
  const size_t i = ((size_t)blockIdx.x * blockDim.x + threadIdx.x) * 8;
  const float4 a = *(const float4*)(s + i);
  const float4 b = *(const float4*)(s + i + 4);
  u16x8 o;
  o[0] = f2bf(a.x); o[1] = f2bf(a.y); o[2] = f2bf(a.z); o[3] = f2bf(a.w);
  o[4] = f2bf(b.x); o[5] = f2bf(b.y); o[6] = f2bf(b.z); o[7] = f2bf(b.w);
  *(u16x8*)(d + i) = o;
}

__global__ void cast_qkv_k(const float* __restrict__ q, const float* __restrict__ k,
                           const float* __restrict__ v, u16* __restrict__ dq,
                           u16* __restrict__ dk, u16* __restrict__ dv) {
  const int z = blockIdx.y;
  cast8(z == 0 ? q : z == 1 ? k : v, z == 0 ? dq : z == 1 ? dk : dv);
}

__global__ void cast_w_k(const float* __restrict__ wq, const float* __restrict__ wk,
                         const float* __restrict__ wv, const float* __restrict__ wo,
                         u16* __restrict__ wqkv, u16* __restrict__ wob) {
  const int z = blockIdx.y;
  const float* s = z == 0 ? wq : z == 1 ? wk : z == 2 ? wv : wo;
  u16* d = z < 3 ? wqkv + (size_t)z * MM : wob;
  cast8(s, d);
}

// ----------------- GEMM: C = A @ B^T + bias (m97 structure) -----------------
template <int OMODE>
__device__ __forceinline__ void gemm_bt_body(const u16* __restrict__ A,
                                             const u16* __restrict__ Bw,
                                             const float* __restrict__ bias,
                                             void* __restrict__ Cv, const int K,
                                             const int ldc, const int ncol0,
                                             const int m0, const int n0) {
  __shared__ u16 As[128 * 32];
  __shared__ u16 Bs[128 * 32];
  const int tid = threadIdx.x;
  const int lane = tid & 63;
  const int w = tid >> 6;
  const int l15 = lane & 15;
  const int lg = lane >> 4;

  f32x4 acc[4][4] = {};

  const int arow = (w >> 1) * 64 + l15;
  const int brow = (w & 1) * 64 + l15;
  const int kfb = lg * 16;

  const int strow = w * 32 + (lane >> 2);
  const u16* Ag = A + (size_t)(m0 + strow) * K + (lane & 3) * 8;
  const u16* Bg = Bw + (size_t)(n0 + strow) * K + (lane & 3) * 8;
  const size_t rstep = (size_t)16 * K;
  char* AsL0 = (char*)As + w * 32 * 64;
  char* AsL1 = AsL0 + 16 * 64;
  char* BsL0 = (char*)Bs + w * 32 * 64;
  char* BsL1 = BsL0 + 16 * 64;

  for (int k0 = 0; k0 < K; k0 += 32) {
    __syncthreads();
    gl16(Ag + k0, AsL0);
    gl16(Ag + k0 + rstep, AsL1);
    gl16(Bg + k0, BsL0);
    gl16(Bg + k0 + rstep, BsL1);
    __syncthreads();
    bf16x8 af[4], bfv[4];
#pragma unroll
    for (int t = 0; t < 4; ++t) {
      af[t] = ldbf8c((char*)As + (arow + t * 16) * 64 + kfb);
      bfv[t] = ldbf8c((char*)Bs + (brow + t * 16) * 64 + kfb);
    }
    __builtin_amdgcn_s_setprio(1);
#pragma unroll
    for (int i = 0; i < 4; ++i)
#pragma unroll
      for (int j = 0; j < 4; ++j) acc[i][j] = mfma16(af[i], bfv[j], acc[i][j]);
    __builtin_amdgcn_s_setprio(0);
  }

  const int mrow = (w >> 1) * 64 + lg * 4;
  const int ncol = (w & 1) * 64 + l15;
#pragma unroll
  for (int j = 0; j < 4; ++j) {
    const int gn = n0 + ncol + j * 16;
    const float bia = bias[gn];
#pragma unroll
    for (int i = 0; i < 4; ++i) {
      const int gmb = m0 + mrow + i * 16;
#pragma unroll
      for (int r = 0; r < 4; ++r) {
        const float val = acc[i][j][r] + bia;
        const int gm = gmb + r;
        if (OMODE == 0) {
          ((float*)Cv)[(size_t)gm * ldc + gn] = val;
        } else if (OMODE == 1) {
          ((u16*)Cv)[(size_t)gm * ldc + ncol0 + gn] = f2bf(val);
        } else {
          const int bb = gm >> 11, ss = gm & 2047;
          const int hh = gn >> 6, dd = gn & 63;
          ((u16*)Cv)[(((size_t)(bb * 16 + hh) * 64 + dd) << 11) + ss] = f2bf(val);
        }
      }
    }
  }
}

// XCD-chunked QKV projections (768 blocks; xcd = b&7).
__global__ __launch_bounds__(256, 3) void gemm_qkv_k(
    const u16* __restrict__ qb, const u16* __restrict__ kb,
    const u16* __restrict__ vb, const u16* __restrict__ wqkv,
    const float* __restrict__ bq, const float* __restrict__ bk,
    const float* __restrict__ bv, u16* __restrict__ proj, u16* __restrict__ vtb) {
  const int b = blockIdx.x;
  const int xcd = b & 7;
  const int i = b >> 3;
  const int z = i >> 5;
  const int j = i & 31;
  const int m0 = (xcd * 4 + (j >> 3)) * 128;
  const int n0 = (j & 7) * 128;
  if (z == 2)
    gemm_bt_body<2>(vb, wqkv + 2 * (size_t)MM, bv, vtb, DMODEL, 0, 0, m0, n0);
  else
    gemm_bt_body<1>(z == 0 ? qb : kb, wqkv + (size_t)z * MM, z == 0 ? bq : bk,
                    proj, DMODEL, LDP, z * DMODEL, m0, n0);
}

__global__ __launch_bounds__(256, 3) void gemm_o_k(const u16* __restrict__ attnb,
                                                   const u16* __restrict__ wob,
                                                   const float* __restrict__ bo,
                                                   float* __restrict__ out) {
  const int b = blockIdx.x;
  const int xcd = b & 7;
  const int i = b >> 3;
  const int m0 = (xcd * 4 + (i >> 3)) * 128;
  const int n0 = (i & 7) * 128;
  gemm_bt_body<0>(attnb, wob, bo, out, DMODEL, DMODEL, 0, m0, n0);
}

// ----------------- flash attention: 32x32 MFMA, zero-exchange P -----------
// 512 blocks (2/CU); xcd = b&7, 4 heads/XCD. Block = 128 q rows; 4 waves,
// wave w owns q = qB + w*32 + l31. hi = lane>>5.
// QK^T = mfma32(K, Q): s reg r holds S[kv = 32*tile + (r&3)+8*(r>>2)+4*hi][q=l31].
// PV per 16-kv chunk uses k-slot map psi(hi,j) = 4*hi + (j&3) + 8*(j>>2):
// B-frag = cvtpk of the lane's OWN regs s[G..G+7] (no cross-lane ops);
// V A-frag element j = V^T[d][kvb + psi(hi,j)] -> 2x ds_read_b64 per row.
__global__ __launch_bounds__(256, 2) void attn_k(const u16* __restrict__ proj,
                                                 const u16* __restrict__ vtb,
                                                 u16* __restrict__ outa) {
  __shared__ u16 ks[2][64 * 64];   // K tile [kv][d], XOR-swizzled
  __shared__ u16 vs[2][64 * 64];   // V^T tile [d][kv], XOR-swizzled
  const int b = blockIdx.x;
  const int slot = b >> 3;
  const int bh = (b & 7) * 4 + (slot >> 4);
  const int qB = (slot & 15) * 128;
  const int tid = threadIdx.x;
  const int lane = tid & 63;
  const int w = tid >> 6;
  const size_t rb = (size_t)(bh >> 4) * SEQ;
  const int h = bh & 15;
  const int l31 = lane & 31;
  const int hi = lane >> 5;
  const int swz = (l31 & 7) << 4;

  // Q B-frags: Q[q][d = km*16 + hi*8 + j]
  const u16* qp = proj + (rb + qB + w * 32 + l31) * LDP + h * 64 + hi * 8;
  bf16x8 qf[4];
#pragma unroll
  for (int km = 0; km < 4; ++km) qf[km] = ldbf8(qp + km * 16);

  // staging: row = tid>>2 (64 rows), 32B at col (tid&3)*32 bytes, swizzled
  const int srow = tid >> 2;
  const int scel = (tid & 3) * 16;
  const int stz0 = srow * 128 + (((tid & 3) * 32) ^ ((srow & 7) << 4));
  const int stz1 = srow * 128 + ((((tid & 3) * 32) + 16) ^ ((srow & 7) << 4));
  const u16* kg = proj + rb * LDP + DMODEL + h * 64;  // K rows, stride LDP
  const u16* vg = vtb + (size_t)bh * 64 * SEQ;        // V^T rows [d][s]

  u16x8 ka0, ka1, va0, va1;
  {
    const u16* kr = kg + (size_t)srow * LDP + scel;
    ka0 = *(const u16x8*)kr;
    ka1 = *(const u16x8*)(kr + 8);
    const u16* vr = vg + (size_t)srow * SEQ + scel;
    va0 = *(const u16x8*)vr;
    va1 = *(const u16x8*)(vr + 8);
  }

  f32x16 oa0 = {}, oa1 = {};
  float mrun = -3.0e38f, lrun = 0.f;
  int p = 0;

  for (int kv0 = 0; kv0 < SEQ; kv0 += 64) {
    {
      char* kd = (char*)ks[p];
      char* vd = (char*)vs[p];
      *(u16x8*)(kd + stz0) = ka0;
      *(u16x8*)(kd + stz1) = ka1;
      *(u16x8*)(vd + stz0) = va0;
      *(u16x8*)(vd + stz1) = va1;
    }
    __syncthreads();  // single barrier per iter
    if (kv0 + 64 < SEQ) {  // prefetch next tile -> regs
      const u16* kr = kg + (size_t)(kv0 + 64 + srow) * LDP + scel;
      ka0 = *(const u16x8*)kr;
      ka1 = *(const u16x8*)(kr + 8);
      const u16* vr = vg + (size_t)srow * SEQ + kv0 + 64 + scel;
      va0 = *(const u16x8*)vr;
      va1 = *(const u16x8*)(vr + 8);
    }
    // ---- QK^T (raw scores) ----
    const char* kp = (const char*)ks[p];
    const char* vp = (const char*)vs[p];
    f32x16 s0 = {}, s1 = {};
    __builtin_amdgcn_s_setprio(1);
#pragma unroll
    for (int km = 0; km < 4; ++km) {
      const int co = (km * 32 + hi * 16) ^ swz;
      const bf16x8 k0 = ldbf8c(kp + l31 * 128 + co);
      const bf16x8 k1 = ldbf8c(kp + (32 + l31) * 128 + co);
      s0 = mfma32(k0, qf[km], s0);
      s1 = mfma32(k1, qf[km], s1);
    }
    __builtin_amdgcn_s_setprio(0);

    // ---- online softmax (raw-domain max; scale folded into exp fma) ----
    float mxq0 = fmaxf(fmaxf(s0[0], s0[1]), fmaxf(s0[2], s0[3]));
    float mxq1 = fmaxf(fmaxf(s0[4], s0[5]), fmaxf(s0[6], s0[7]));
    float mxq2 = fmaxf(fmaxf(s0[8], s0[9]), fmaxf(s0[10], s0[11]));
    float mxq3 = fmaxf(fmaxf(s0[12], s0[13]), fmaxf(s0[14], s0[15]));
    float mxq4 = fmaxf(fmaxf(s1[0], s1[1]), fmaxf(s1[2], s1[3]));
    float mxq5 = fmaxf(fmaxf(s1[4], s1[5]), fmaxf(s1[6], s1[7]));
    float mxq6 = fmaxf(fmaxf(s1[8], s1[9]), fmaxf(s1[10], s1[11]));
    float mxq7 = fmaxf(fmaxf(s1[12], s1[13]), fmaxf(s1[14], s1[15]));
    float mx = fmaxf(fmaxf(fmaxf(mxq0, mxq1), fmaxf(mxq2, mxq3)),
                     fmaxf(fmaxf(mxq4, mxq5), fmaxf(mxq6, mxq7)));
    mx = fmaxf(mx, __shfl_xor(mx, 32));
    // defer-max: 64.0 raw == 8/ln2 in scaled-log2 domain
    if (!__all(mx <= mrun + 64.0f)) {
      const float mn = fmaxf(mrun, mx);
      const float sf = fexp2((mrun - mn) * SC);
      mrun = mn;
      lrun *= sf;
#pragma unroll
      for (int r = 0; r < 16; ++r) { oa0[r] *= sf; oa1[r] *= sf; }
    }
    const float nmc = -mrun * SC;
#pragma unroll
    for (int r = 0; r < 16; ++r) s0[r] = fexp2(__builtin_fmaf(s0[r], SC, nmc));
#pragma unroll
    for (int r = 0; r < 16; ++r) s1[r] = fexp2(__builtin_fmaf(s1[r], SC, nmc));
    float rs = (((s0[0] + s0[1]) + (s0[2] + s0[3])) +
                ((s0[4] + s0[5]) + (s0[6] + s0[7]))) +
               (((s0[8] + s0[9]) + (s0[10] + s0[11])) +
                ((s0[12] + s0[13]) + (s0[14] + s0[15])));
    rs += (((s1[0] + s1[1]) + (s1[2] + s1[3])) +
           ((s1[4] + s1[5]) + (s1[6] + s1[7]))) +
          (((s1[8] + s1[9]) + (s1[10] + s1[11])) +
           ((s1[12] + s1[13]) + (s1[14] + s1[15])));
    rs += __shfl_xor(rs, 32);
    lrun += rs;

    // ---- PV: 4 chunks of 16 kv; P from own regs only ----
    __builtin_amdgcn_s_setprio(1);
#define PCHUNK(SV, G, CB)                                                \
    {                                                                    \
      u16x8 pbu;                                                         \
      ((u32*)&pbu)[0] = cvtpk(SV[G + 0], SV[G + 1]);                     \
      ((u32*)&pbu)[1] = cvtpk(SV[G + 2], SV[G + 3]);                     \
      ((u32*)&pbu)[2] = cvtpk(SV[G + 4], SV[G + 5]);                     \
      ((u32*)&pbu)[3] = cvtpk(SV[G + 6], SV[G + 7]);                     \
      const bf16x8 pb = __builtin_bit_cast(bf16x8, pbu);                 \
      const int vc0 = (CB + 8 * hi) ^ swz;                               \
      const int vc1 = (CB + 16 + 8 * hi) ^ swz;                          \
      const char* vr0 = vp + l31 * 128;                                  \
      const char* vr1 = vp + (32 + l31) * 128;                           \
      u16x8 vf0, vf1;                                                    \
      *(u16x4*)&vf0       = *(const u16x4*)(vr0 + vc0);                  \
      *((u16x4*)&vf0 + 1) = *(const u16x4*)(vr0 + vc1);                  \
      *(u16x4*)&vf1       = *(const u16x4*)(vr1 + vc0);                  \
      *((u16x4*)&vf1 + 1) = *(const u16x4*)(vr1 + vc1);                  \
      oa0 = mfma32(__builtin_bit_cast(bf16x8, vf0), pb, oa0);            \
      oa1 = mfma32(__builtin_bit_cast(bf16x8, vf1), pb, oa1);            \
    }
    PCHUNK(s0, 0, 0)
    PCHUNK(s0, 8, 32)
    PCHUNK(s1, 0, 64)
    PCHUNK(s1, 8, 96)
#undef PCHUNK
    __builtin_amdgcn_s_setprio(0);
    p ^= 1;
  }

  // ---- epilogue: O^T[d][q] -> attnb[q][h*64+d] ----
  const float invl = 1.0f / lrun;
  u16* orow = outa + (rb + qB + w * 32 + l31) * DMODEL + h * 64 + hi * 4;
#pragma unroll
  for (int g = 0; g < 4; ++g) {
    u16x4 st0, st1;
    ((u32*)&st0)[0] = cvtpk(oa0[4 * g + 0] * invl, oa0[4 * g + 1] * invl);
    ((u32*)&st0)[1] = cvtpk(oa0[4 * g + 2] * invl, oa0[4 * g + 3] * invl);
    *(u16x4*)(orow + 8 * g) = st0;
    ((u32*)&st1)[0] = cvtpk(oa1[4 * g + 0] * invl, oa1[4 * g + 1] * invl);
    ((u32*)&st1)[1] = cvtpk(oa1[4 * g + 2] * invl, oa1[4 * g + 3] * invl);
    *(u16x4*)(orow + 32 + 8 * g) = st1;
  }
}

extern "C" void kernel_launch(void* const* d_in, const int* in_sizes, int n_in,
                              void* d_out, int out_size, void* d_ws, size_t ws_size,
                              hipStream_t stream) {
  const float* q  = (const float*)d_in[0];
  const float* k  = (const float*)d_in[1];
  const float* v  = (const float*)d_in[2];
  const float* wq = (const float*)d_in[3];
  const float* bq = (const float*)d_in[4];
  const float* wk = (const float*)d_in[5];
  const float* bk = (const float*)d_in[6];
  const float* wv = (const float*)d_in[7];
  const float* bv = (const float*)d_in[8];
  const float* wo = (const float*)d_in[9];
  const float* bo = (const float*)d_in[10];

  const size_t NTOK = (size_t)2 * SEQ;
  const size_t NELE = NTOK * DMODEL;
  u16* qb    = (u16*)d_ws;
  u16* kb    = qb + NELE;
  u16* vb    = kb + NELE;
  u16* wqkv  = vb + NELE;
  u16* wob   = wqkv + 3 * (size_t)MM;
  u16* projb = wob + (size_t)MM;
  u16* vtb   = projb + NTOK * LDP;
  u16* attnb = qb;  // qb dead after projections -> reuse

  cast_qkv_k<<<dim3(2048, 3), 256, 0, stream>>>(q, k, v, qb, kb, vb);
  cast_w_k<<<dim3(512, 4), 256, 0, stream>>>(wq, wk, wv, wo, wqkv, wob);
  gemm_qkv_k<<<768, 256, 0, stream>>>(qb, kb, vb, wqkv, bq, bk, bv, projb, vtb);
  attn_k<<<512, 256, 0, stream>>>(projb, vtb, attnb);
  gemm_o_k<<<256, 256, 0, stream>>>(attnb, wob, bo, (float*)d_out);
}